// Round 1
// baseline (255.050 us; speedup 1.0000x reference)
//
#include <hip/hip_runtime.h>
#include <hip/hip_bf16.h>
#include <stdint.h>

#define NB   16
#define CIN  256
#define CRED 64
#define HW   2304
#define NJT  36   // 2304/64

typedef __bf16 bf16;
typedef __bf16 bf16x8 __attribute__((ext_vector_type(8)));
typedef __bf16 bf16x4 __attribute__((ext_vector_type(4)));
typedef float  f32x4  __attribute__((ext_vector_type(4)));

// ---------------- Kernel 1: fused QKV 1x1 convs ----------------
// x [N][256][2304] f32 -> qT [N][2304][64] bf16, kT [N][2304][64] bf16, v [N][64][2304] bf16
__global__ __launch_bounds__(256) void qkv_kernel(
    const float* __restrict__ x,
    const float* __restrict__ Wq, const float* __restrict__ bq,
    const float* __restrict__ Wk, const float* __restrict__ bk,
    const float* __restrict__ Wv, const float* __restrict__ bv,
    bf16* __restrict__ qT, bf16* __restrict__ kT, bf16* __restrict__ v)
{
    __shared__ __align__(16) bf16 sX[64 * 264];  // xT[pos][cin], stride 264 (pad 8)
    const int jt = blockIdx.x, n = blockIdx.y;
    const int jbase = jt * 64;
    const int tid = threadIdx.x;
    const int lane = tid & 63, w = tid >> 6;
    const int l15 = lane & 15, q4 = lane >> 4;

    // stage xT (transpose + cvt bf16): coalesced float4 reads, scalar LDS writes
    const float* xn = x + ((size_t)n * CIN) * HW + jbase;
    #pragma unroll
    for (int it = 0; it < 16; ++it) {
        int idx = tid + 256 * it;          // 4096 float4s total
        int c = idx >> 4, p4 = idx & 15;
        const float4 vv = *(const float4*)(xn + c * HW + p4 * 4);
        sX[(p4 * 4 + 0) * 264 + c] = (bf16)vv.x;
        sX[(p4 * 4 + 1) * 264 + c] = (bf16)vv.y;
        sX[(p4 * 4 + 2) * 264 + c] = (bf16)vv.z;
        sX[(p4 * 4 + 3) * 264 + c] = (bf16)vv.w;
    }
    __syncthreads();

    const float* Ws[3] = {Wq, Wk, Wv};
    const float* bs[3] = {bq, bk, bv};
    #pragma unroll
    for (int wi = 0; wi < 3; ++wi) {
        // A-frags from global weights (L2-resident), cvt to bf16
        bf16x8 a[8];
        const float* Wp = Ws[wi] + (w * 16 + l15) * CIN + q4 * 8;
        #pragma unroll
        for (int ks = 0; ks < 8; ++ks) {
            float4 f0 = *(const float4*)(Wp + ks * 32);
            float4 f1 = *(const float4*)(Wp + ks * 32 + 4);
            bf16x8 t = {(bf16)f0.x, (bf16)f0.y, (bf16)f0.z, (bf16)f0.w,
                        (bf16)f1.x, (bf16)f1.y, (bf16)f1.z, (bf16)f1.w};
            a[ks] = t;
        }
        f32x4 acc[4] = {};
        #pragma unroll
        for (int nt = 0; nt < 4; ++nt) {
            #pragma unroll
            for (int ks = 0; ks < 8; ++ks) {
                bf16x8 b = *(const bf16x8*)(sX + (nt * 16 + l15) * 264 + ks * 32 + q4 * 8);
                acc[nt] = __builtin_amdgcn_mfma_f32_16x16x32_bf16(a[ks], b, acc[nt], 0, 0, 0);
            }
        }
        const int crb = w * 16 + q4 * 4;   // C/D row = outc
        const float b0 = bs[wi][crb], b1 = bs[wi][crb + 1],
                    b2 = bs[wi][crb + 2], b3 = bs[wi][crb + 3];
        if (wi < 2) {
            bf16* dst = (wi == 0 ? qT : kT) + ((size_t)n * HW) * 64;
            #pragma unroll
            for (int nt = 0; nt < 4; ++nt) {
                int pos = jbase + nt * 16 + l15;
                bf16x4 pk = {(bf16)(acc[nt].x + b0), (bf16)(acc[nt].y + b1),
                             (bf16)(acc[nt].z + b2), (bf16)(acc[nt].w + b3)};
                *(bf16x4*)(dst + pos * 64 + crb) = pk;
            }
        } else {
            bf16* dst = v + ((size_t)n * CRED) * HW;
            #pragma unroll
            for (int nt = 0; nt < 4; ++nt) {
                int pos = jbase + nt * 16 + l15;
                dst[(crb + 0) * HW + pos] = (bf16)(acc[nt].x + b0);
                dst[(crb + 1) * HW + pos] = (bf16)(acc[nt].y + b1);
                dst[(crb + 2) * HW + pos] = (bf16)(acc[nt].z + b2);
                dst[(crb + 3) * HW + pos] = (bf16)(acc[nt].w + b3);
            }
        }
    }
}

// ---------------- Kernel 2: fused KtQ -> exp -> V*P (global softmax, no max needed) ----
// qT/kT [N][2304][64] bf16, v [N][64][2304] bf16 -> OT [N][2304][64] f32 (unnormalized), Z[N]
__global__ __launch_bounds__(256) void attn_kernel(
    const bf16* __restrict__ qT, const bf16* __restrict__ kT,
    const bf16* __restrict__ v,
    float* __restrict__ OT, float* __restrict__ Z)
{
    __shared__ __align__(16) bf16 sQ[64 * 72];
    __shared__ __align__(16) bf16 sK[64 * 72];
    __shared__ __align__(16) bf16 sV[64 * 72];
    __shared__ __align__(16) bf16 sP[64 * 72];
    const int jt = blockIdx.x, n = blockIdx.y;
    const int jbase = jt * 64;
    const int tid = threadIdx.x;
    const int lane = tid & 63, w = tid >> 6;
    const int l15 = lane & 15, q4 = lane >> 4;

    // stage Q tile once: straight copy (qT rows are contiguous 64 bf16 = 8 uint4)
    {
        const uint4* src = (const uint4*)(qT + ((size_t)n * HW + jbase) * 64);
        uint4* dst = (uint4*)sQ;
        for (int i = tid; i < 512; i += 256) {
            int r = i >> 3, c = i & 7;
            dst[r * 9 + c] = src[r * 8 + c];
        }
    }
    f32x4 oacc[4] = {};
    float zacc = 0.f;
    const uint4* ksrc = (const uint4*)(kT + ((size_t)n * HW) * 64);
    const bf16* vbase = v + ((size_t)n * CRED) * HW;

    for (int ib = 0; ib < NJT; ++ib) {
        const int ibase = ib * 64;
        __syncthreads();   // prior iter's reads of sK/sV/sP done
        {   // stage K tile (straight copy) and V tile (row segments)
            uint4* dk = (uint4*)sK;
            uint4* dv = (uint4*)sV;
            const uint4* sk = ksrc + ibase * 8;
            for (int i = tid; i < 512; i += 256) {
                int r = i >> 3, c = i & 7;
                dk[r * 9 + c] = sk[r * 8 + c];
                dv[r * 9 + c] = *(const uint4*)(vbase + r * HW + ibase + c * 8);
            }
        }
        __syncthreads();
        // S = K_i^T Q_j : wave w owns i-rows [16w,16w+16), all 64 j
        f32x4 s[4];
        #pragma unroll
        for (int nt = 0; nt < 4; ++nt) {
            f32x4 accs = {};
            #pragma unroll
            for (int ks = 0; ks < 2; ++ks) {
                bf16x8 afr = *(const bf16x8*)(sK + (w * 16 + l15) * 72 + ks * 32 + q4 * 8);
                bf16x8 bfr = *(const bf16x8*)(sQ + (nt * 16 + l15) * 72 + ks * 32 + q4 * 8);
                accs = __builtin_amdgcn_mfma_f32_16x16x32_bf16(afr, bfr, accs, 0, 0, 0);
            }
            s[nt] = accs;
        }
        // exp (fp32, no shift: logits bounded ~|q||k|<21 so exp<1.3e9 fits fp32), Z partial,
        // write P transposed into B-operand layout sP[j][i]
        #pragma unroll
        for (int nt = 0; nt < 4; ++nt) {
            float p0 = __expf(s[nt].x), p1 = __expf(s[nt].y);
            float p2 = __expf(s[nt].z), p3 = __expf(s[nt].w);
            zacc += (p0 + p1) + (p2 + p3);
            bf16x4 pk = {(bf16)p0, (bf16)p1, (bf16)p2, (bf16)p3};
            *(bf16x4*)(sP + (nt * 16 + l15) * 72 + w * 16 + q4 * 4) = pk;
        }
        __syncthreads();
        // O += V_i * P : wave w owns c-rows [16w,16w+16)
        #pragma unroll
        for (int nt = 0; nt < 4; ++nt) {
            #pragma unroll
            for (int ks = 0; ks < 2; ++ks) {
                bf16x8 afr = *(const bf16x8*)(sV + (w * 16 + l15) * 72 + ks * 32 + q4 * 8);
                bf16x8 bfr = *(const bf16x8*)(sP + (nt * 16 + l15) * 72 + ks * 32 + q4 * 8);
                oacc[nt] = __builtin_amdgcn_mfma_f32_16x16x32_bf16(afr, bfr, oacc[nt], 0, 0, 0);
            }
        }
    }
    // write unnormalized O transposed: OT[pos][cr] (float4 straight from C-layout)
    float* OTn = OT + ((size_t)n * HW) * 64;
    #pragma unroll
    for (int nt = 0; nt < 4; ++nt) {
        int pos = jbase + nt * 16 + l15;
        *(f32x4*)(OTn + pos * 64 + w * 16 + q4 * 4) = oacc[nt];
    }
    // per-batch Z: wave reduce then one atomic per wave
    #pragma unroll
    for (int off = 32; off > 0; off >>= 1) zacc += __shfl_down(zacc, off);
    if (lane == 0) atomicAdd(Z + n, zacc);
}

// ---------------- Kernel 3: out = g * (Watt @ (O/Z) + batt) + g ----------------
__global__ __launch_bounds__(256) void out_kernel(
    const float* __restrict__ OT, const float* __restrict__ Z,
    const float* __restrict__ Watt, const float* __restrict__ batt,
    const float* __restrict__ g, float* __restrict__ out)
{
    __shared__ __align__(16) bf16 sO[64 * 72];  // normalized O, [pos][cr]
    const int jt = blockIdx.x, n = blockIdx.y;
    const int jbase = jt * 64;
    const int tid = threadIdx.x;
    const int lane = tid & 63, w = tid >> 6;
    const int l15 = lane & 15, q4 = lane >> 4;
    const float invZ = 1.0f / Z[n];

    const float* On = OT + ((size_t)n * HW + jbase) * 64;
    for (int i = tid; i < 1024; i += 256) {
        int r = i >> 4, c4 = i & 15;
        float4 vv = *(const float4*)(On + r * 64 + c4 * 4);
        bf16x4 pk = {(bf16)(vv.x * invZ), (bf16)(vv.y * invZ),
                     (bf16)(vv.z * invZ), (bf16)(vv.w * invZ)};
        *(bf16x4*)(sO + r * 72 + c4 * 4) = pk;
    }
    __syncthreads();

    // wave w owns co in [64w, 64w+64): 4 m-tiles
    bf16x8 a[4][2];
    #pragma unroll
    for (int mt = 0; mt < 4; ++mt) {
        const float* Wp = Watt + (w * 64 + mt * 16 + l15) * 64 + q4 * 8;
        #pragma unroll
        for (int ks = 0; ks < 2; ++ks) {
            float4 f0 = *(const float4*)(Wp + ks * 32);
            float4 f1 = *(const float4*)(Wp + ks * 32 + 4);
            bf16x8 t = {(bf16)f0.x, (bf16)f0.y, (bf16)f0.z, (bf16)f0.w,
                        (bf16)f1.x, (bf16)f1.y, (bf16)f1.z, (bf16)f1.w};
            a[mt][ks] = t;
        }
    }
    const float* gp = g + ((size_t)n * CIN) * HW;
    float* op = out + ((size_t)n * CIN) * HW;
    #pragma unroll
    for (int mt = 0; mt < 4; ++mt) {
        #pragma unroll
        for (int nt = 0; nt < 4; ++nt) {
            f32x4 acc = {};
            #pragma unroll
            for (int ks = 0; ks < 2; ++ks) {
                bf16x8 b = *(const bf16x8*)(sO + (nt * 16 + l15) * 72 + ks * 32 + q4 * 8);
                acc = __builtin_amdgcn_mfma_f32_16x16x32_bf16(a[mt][ks], b, acc, 0, 0, 0);
            }
            const int co = w * 64 + mt * 16 + q4 * 4;
            const int pos = jbase + nt * 16 + l15;
            const float b0 = batt[co], b1 = batt[co + 1], b2 = batt[co + 2], b3 = batt[co + 3];
            const float g0 = gp[(co + 0) * HW + pos], g1 = gp[(co + 1) * HW + pos];
            const float g2 = gp[(co + 2) * HW + pos], g3 = gp[(co + 3) * HW + pos];
            op[(co + 0) * HW + pos] = g0 * (acc.x + b0 + 1.0f);
            op[(co + 1) * HW + pos] = g1 * (acc.y + b1 + 1.0f);
            op[(co + 2) * HW + pos] = g2 * (acc.z + b2 + 1.0f);
            op[(co + 3) * HW + pos] = g3 * (acc.w + b3 + 1.0f);
        }
    }
}

extern "C" void kernel_launch(void* const* d_in, const int* in_sizes, int n_in,
                              void* d_out, int out_size, void* d_ws, size_t ws_size,
                              hipStream_t stream) {
    const float* x    = (const float*)d_in[0];
    const float* g    = (const float*)d_in[1];
    const float* Wq   = (const float*)d_in[2];
    const float* bq   = (const float*)d_in[3];
    const float* Wk   = (const float*)d_in[4];
    const float* bk   = (const float*)d_in[5];
    const float* Wv   = (const float*)d_in[6];
    const float* bv   = (const float*)d_in[7];
    const float* Watt = (const float*)d_in[8];
    const float* batt = (const float*)d_in[9];
    float* out = (float*)d_out;

    char* ws = (char*)d_ws;
    const size_t qkv_sz = (size_t)NB * HW * CRED * sizeof(bf16);   // 4,718,592
    bf16*  qT = (bf16*)(ws);
    bf16*  kT = (bf16*)(ws + qkv_sz);
    bf16*  vv = (bf16*)(ws + 2 * qkv_sz);
    float* OT = (float*)(ws + 3 * qkv_sz);                         // 9,437,184 B
    float* Z  = (float*)(ws + 3 * qkv_sz + (size_t)NB * HW * CRED * sizeof(float));

    hipMemsetAsync(Z, 0, NB * sizeof(float), stream);

    dim3 grid(NJT, NB), blk(256);
    qkv_kernel<<<grid, blk, 0, stream>>>(x, Wq, bq, Wk, bk, Wv, bv, qT, kT, vv);
    attn_kernel<<<grid, blk, 0, stream>>>(qT, kT, vv, OT, Z);
    out_kernel<<<grid, blk, 0, stream>>>(OT, Z, Watt, batt, g, out);
}